// Round 5
// baseline (305.565 us; speedup 1.0000x reference)
//
#include <hip/hip_runtime.h>

#define K_DIM  512
#define C_DIM  4096
#define RB     128           // x-rows per workgroup
#define CT     512           // codes per tile
#define NCT    (C_DIM / CT)  // 8
#define NKS    16            // K-steps of 32 per tile
#define NPH    (NCT * NKS)   // 128 total phases
#define ROWB   1024          // bytes per fp16 row (512 * 2)
#define BUFSZ  40960         // per LDS buf: Es 32KB + Xs 8KB

typedef __attribute__((ext_vector_type(4))) float    f32x4;
typedef _Float16 __attribute__((ext_vector_type(8))) f16x8;

__device__ __forceinline__ void load16(const void* g, void* s) {
    __builtin_amdgcn_global_load_lds(
        (const __attribute__((address_space(1))) unsigned int*)g,
        (__attribute__((address_space(3))) unsigned int*)s, 16, 0, 0);
}

// prepass: x -> X1 fp16 (in d_out), e -> E1 fp16 (in ws)
__global__ __launch_bounds__(256)
void convert_f16(const float* __restrict__ x, const float* __restrict__ e,
                 _Float16* __restrict__ X1, _Float16* __restrict__ E1, int xblocks) {
    const long bid = blockIdx.x;
    const float* src; _Float16* dst; long base;
    if (bid < xblocks) { src = x; dst = X1; base = (bid * 256 + threadIdx.x) * 8L; }
    else               { src = e; dst = E1; base = ((bid - xblocks) * 256 + threadIdx.x) * 8L; }
    float4 v0 = *(const float4*)(src + base);
    float4 v1 = *(const float4*)(src + base + 4);
    f16x8 h;
    h[0] = (_Float16)v0.x; h[1] = (_Float16)v0.y; h[2] = (_Float16)v0.z; h[3] = (_Float16)v0.w;
    h[4] = (_Float16)v1.x; h[5] = (_Float16)v1.y; h[6] = (_Float16)v1.z; h[7] = (_Float16)v1.w;
    *(f16x8*)(dst + base) = h;
}

// fp16 proxy GEMM (swapped operands: MFMA A = codes, B = x-rows) + top-4 candidates.
// 8 waves = 4 code-groups x 2 row-groups; wave tile = 128 codes x 64 rows.
// Triple-buffered LDS, depth-2 prefetch, counted vmcnt (T4): loads span barriers.
__global__ __launch_bounds__(512, 2)
void vq_gemm(const _Float16* __restrict__ X1,
             const _Float16* __restrict__ E1,
             int* __restrict__ cand) {
    extern __shared__ unsigned char lds[];   // 3 * BUFSZ = 120 KB

    const int tid = threadIdx.x;
    const int l   = tid & 63;
    const int wid = tid >> 6;     // 0..7
    const int wc  = wid & 3;      // code group: codes wc*128..+128 within tile
    const int wr  = wid >> 2;     // row group: rows wr*64..+64
    const long row0 = (long)blockIdx.x * RB;

    // swizzle s(row) = (row>>1)&3 -> 2-way residual (free). Both-sides (rule #21).
    auto stage = [&](int buf, int k) {
        const int ct = k >> 4, t = k & 15;
        unsigned char* base = lds + buf * BUFSZ;
        {   // X slice: 128 rows x 64 B
            int row = wid * 16 + (l >> 2);
            int c   = l & 3;
            const unsigned char* g = (const unsigned char*)X1
                + (row0 + row) * ROWB + t * 64 + ((c ^ ((row >> 1) & 3)) << 4);
            load16(g, base + 32768 + wid * 1024);
        }
#pragma unroll
        for (int h = 0; h < 4; ++h) {   // E slice: 512 rows x 64 B
            int row = wid * 64 + h * 16 + (l >> 2);
            int c   = l & 3;
            const unsigned char* g = (const unsigned char*)E1
                + (long)(ct * CT + row) * ROWB + t * 64 + ((c ^ ((row >> 1) & 3)) << 4);
            load16(g, base + wid * 4096 + h * 1024);
        }
    };

    // per-lane running top-2 (per xn block)
    float q0[4], q1[4]; int i0[4], i1[4];
#pragma unroll
    for (int xn = 0; xn < 4; ++xn) { q0[xn] = -3.0e38f; q1[xn] = -3.0e38f; i0[xn] = 0; i1[xn] = 0; }

    f32x4 acc[8][4];

    stage(0, 0);
    stage(1, 1);
    asm volatile("s_waitcnt vmcnt(5)" ::: "memory");   // buf0 landed; buf1's 5 in flight
    __builtin_amdgcn_s_barrier();

    int cur = 0;
    for (int ct = 0; ct < NCT; ++ct) {
#pragma unroll
        for (int cm = 0; cm < 8; ++cm)
#pragma unroll
            for (int xn = 0; xn < 4; ++xn) acc[cm][xn] = (f32x4){0.f, 0.f, 0.f, 0.f};

        for (int t = 0; t < NKS; ++t) {
            const int k = ct * NKS + t;
            const unsigned char* Es = lds + cur * BUFSZ;
            const unsigned char* Xs = Es + 32768;
            const int g = l >> 4;

            f16x8 afr[8], bfr[4];
#pragma unroll
            for (int cm = 0; cm < 8; ++cm) {
                int row = wc * 128 + cm * 16 + (l & 15);
                afr[cm] = *(const f16x8*)(Es + row * 64 + ((g ^ ((row >> 1) & 3)) << 4));
            }
#pragma unroll
            for (int xn = 0; xn < 4; ++xn) {
                int row = wr * 64 + xn * 16 + (l & 15);
                bfr[xn] = *(const f16x8*)(Xs + row * 64 + ((g ^ ((row >> 1) & 3)) << 4));
            }

            // depth-2 prefetch into the buffer whose last readers finished a barrier ago
            int nb = cur + 2; if (nb >= 3) nb -= 3;
            const bool more = (k + 2 < NPH);
            if (more) stage(nb, k + 2);

            __builtin_amdgcn_s_setprio(1);
#pragma unroll
            for (int cm = 0; cm < 8; ++cm)
#pragma unroll
                for (int xn = 0; xn < 4; ++xn)
                    acc[cm][xn] = __builtin_amdgcn_mfma_f32_16x16x32_f16(
                        afr[cm], bfr[xn], acc[cm][xn], 0, 0, 0);
            __builtin_amdgcn_s_setprio(0);

            // end-of-tile top-2 insert BEFORE the wait: VALU overlaps load latency
            if (t == NKS - 1) {
                const int cbase = ct * CT + wc * 128 + (l >> 4) * 4;
#pragma unroll
                for (int xn = 0; xn < 4; ++xn) {
#pragma unroll
                    for (int cm = 0; cm < 8; ++cm)
#pragma unroll
                        for (int j = 0; j < 4; ++j) {
                            float v = acc[cm][xn][j];
                            int  cc = cbase + cm * 16 + j;
                            bool b0 = v > q0[xn];
                            bool b1 = v > q1[xn];
                            q1[xn] = b1 ? (b0 ? q0[xn] : v)  : q1[xn];
                            i1[xn] = b1 ? (b0 ? i0[xn] : cc) : i1[xn];
                            q0[xn] = b0 ? v  : q0[xn];
                            i0[xn] = b0 ? cc : i0[xn];
                        }
                }
            }

            // counted vmcnt: keep this phase's 5 stage-loads in flight (never drain mid-loop)
            if (more) { asm volatile("s_waitcnt vmcnt(5)" ::: "memory"); }
            else      { asm volatile("s_waitcnt vmcnt(0)" ::: "memory"); }
            __builtin_amdgcn_s_barrier();

            cur = (cur == 2) ? 0 : cur + 1;
        }
    }

    // merge: 32 candidates/row via LDS -> exact top-4 -> cand[]
    // (last phase ended with vmcnt(0)+barrier: all LDS traffic done, safe to reuse)
    float2* cl = (float2*)lds;            // [128 rows][32 slots]
    const int g4 = l >> 4;
#pragma unroll
    for (int xn = 0; xn < 4; ++xn) {
        int rl = wr * 64 + xn * 16 + (l & 15);
        cl[rl * 32 + wc * 8 + g4 * 2 + 0] = make_float2(q0[xn], __int_as_float(i0[xn]));
        cl[rl * 32 + wc * 8 + g4 * 2 + 1] = make_float2(q1[xn], __int_as_float(i1[xn]));
    }
    __syncthreads();

    if (tid < RB) {
        float t0 = -3.0e38f, t1 = -3.0e38f, t2 = -3.0e38f, t3 = -3.0e38f;
        int   u0 = 0, u1 = 0, u2 = 0, u3 = 0;
        for (int kk = 0; kk < 32; ++kk) {
            float2 p = cl[tid * 32 + kk];
            float v = p.x; int cc = __float_as_int(p.y);
            bool b0 = v > t0, b1 = v > t1, b2 = v > t2, b3 = v > t3;
            t3 = b3 ? (b2 ? t2 : v)  : t3;  u3 = b3 ? (b2 ? u2 : cc) : u3;
            t2 = b2 ? (b1 ? t1 : v)  : t2;  u2 = b2 ? (b1 ? u1 : cc) : u2;
            t1 = b1 ? (b0 ? t0 : v)  : t1;  u1 = b1 ? (b0 ? u0 : cc) : u1;
            t0 = b0 ? v : t0;               u0 = b0 ? cc : u0;
        }
        int4 w; w.x = u0; w.y = u1; w.z = u2; w.w = u3;
        *(int4*)(cand + (row0 + tid) * 4) = w;
    }
}

// exact fp32 rerank of the 4 candidates + gather e[winner] -> out
__global__ __launch_bounds__(256)
void rerank_gather(const float* __restrict__ x, const float* __restrict__ e,
                   const int* __restrict__ cand, float* __restrict__ out) {
    const int tid = threadIdx.x;
    const int l   = tid & 63;
    const int w   = tid >> 6;
    const long row = (long)blockIdx.x * 4 + w;

    const float* xr = x + row * K_DIM + l * 8;
    f32x4 xv0 = *(const f32x4*)(xr);
    f32x4 xv1 = *(const f32x4*)(xr + 4);

    float d[4]; int c[4];
#pragma unroll
    for (int i = 0; i < 4; ++i) {
        c[i] = cand[row * 4 + i];
        const float* er = e + (long)c[i] * K_DIM + l * 8;
        f32x4 ev0 = *(const f32x4*)(er);
        f32x4 ev1 = *(const f32x4*)(er + 4);
        float s = 0.0f;
        s = fmaf(xv0[0], ev0[0], s); s = fmaf(xv0[1], ev0[1], s);
        s = fmaf(xv0[2], ev0[2], s); s = fmaf(xv0[3], ev0[3], s);
        s = fmaf(xv1[0], ev1[0], s); s = fmaf(xv1[1], ev1[1], s);
        s = fmaf(xv1[2], ev1[2], s); s = fmaf(xv1[3], ev1[3], s);
        d[i] = s;
    }
#pragma unroll
    for (int m = 1; m < 64; m <<= 1)
#pragma unroll
        for (int i = 0; i < 4; ++i) d[i] += __shfl_xor(d[i], m);

    float bv = d[0]; int bc = c[0];
#pragma unroll
    for (int i = 1; i < 4; ++i)
        if (d[i] > bv || (d[i] == bv && c[i] < bc)) { bv = d[i]; bc = c[i]; }

    const float4* src = (const float4*)(e + (long)bc * K_DIM) + l * 2;
    float4*       dst = (float4*)(out + row * K_DIM) + l * 2;
    dst[0] = src[0];
    dst[1] = src[1];
}

extern "C" void kernel_launch(void* const* d_in, const int* in_sizes, int n_in,
                              void* d_out, int out_size, void* d_ws, size_t ws_size,
                              hipStream_t stream) {
    const float* x = (const float*)d_in[0];   // [M, 512] fp32
    const float* e = (const float*)d_in[1];   // [4096, 512] fp32
    float* out = (float*)d_out;

    const int M  = in_sizes[0] / K_DIM;       // 32768
    const int Ce = in_sizes[1] / K_DIM;       // 4096

    _Float16* X1 = (_Float16*)d_out;                                   // 32 MiB, dead before out written
    _Float16* E1 = (_Float16*)d_ws;                                    // 4 MiB
    int* cand    = (int*)((char*)d_ws + (size_t)Ce * K_DIM * 2);       // M*4 ints

    const int xb = M / 4, eb = Ce / 4;
    convert_f16<<<xb + eb, 256, 0, stream>>>(x, e, X1, E1, xb);
    vq_gemm<<<M / RB, 512, 3 * BUFSZ, stream>>>(X1, E1, cand);
    rerank_gather<<<M / 4, 256, 0, stream>>>(x, e, cand, out);
}

// Round 6
// 234.206 us; speedup vs baseline: 1.3047x; 1.3047x over previous
//
#include <hip/hip_runtime.h>

#define K_DIM  512
#define C_DIM  4096
#define RB     128           // x-rows per workgroup
#define CT     512           // codes per tile
#define NCT    (C_DIM / CT)  // 8
#define NKS    16            // K-steps of 32 per tile
#define ROWB   1024          // bytes per fp16 row (512 * 2)

typedef __attribute__((ext_vector_type(4)))  float    f32x4;
typedef __attribute__((ext_vector_type(16))) float    f32x16;
typedef _Float16 __attribute__((ext_vector_type(8)))  f16x8;

__device__ __forceinline__ void load16(const void* g, void* s) {
    __builtin_amdgcn_global_load_lds(
        (const __attribute__((address_space(1))) unsigned int*)g,
        (__attribute__((address_space(3))) unsigned int*)s, 16, 0, 0);
}

// prepass: x -> X1 fp16 (in d_out), e -> E1 fp16 (in ws)
__global__ __launch_bounds__(256)
void convert_f16(const float* __restrict__ x, const float* __restrict__ e,
                 _Float16* __restrict__ X1, _Float16* __restrict__ E1, int xblocks) {
    const long bid = blockIdx.x;
    const float* src; _Float16* dst; long base;
    if (bid < xblocks) { src = x; dst = X1; base = (bid * 256 + threadIdx.x) * 8L; }
    else               { src = e; dst = E1; base = ((bid - xblocks) * 256 + threadIdx.x) * 8L; }
    float4 v0 = *(const float4*)(src + base);
    float4 v1 = *(const float4*)(src + base + 4);
    f16x8 h;
    h[0] = (_Float16)v0.x; h[1] = (_Float16)v0.y; h[2] = (_Float16)v0.z; h[3] = (_Float16)v0.w;
    h[4] = (_Float16)v1.x; h[5] = (_Float16)v1.y; h[6] = (_Float16)v1.z; h[7] = (_Float16)v1.w;
    *(f16x8*)(dst + base) = h;
}

// fp16 proxy GEMM (swapped operands: MFMA A = codes, B = x-rows) + top-4 candidates.
// R4 structure (proven): 2-buf LDS, stage-at-top, __syncthreads per phase.
// MFMA 32x32x16: wave tile = 4 code-tiles x 2 row-tiles of 32x32; 16 MFMA/phase.
// LDS: Es dbuf 2x32KB at [0]; Xs dbuf 2x8KB at [65536]; 80 KB dynamic.
__global__ __launch_bounds__(512, 2)
void vq_gemm(const _Float16* __restrict__ X1,
             const _Float16* __restrict__ E1,
             int* __restrict__ cand) {
    extern __shared__ unsigned char lds[];

    const int tid = threadIdx.x;
    const int l   = tid & 63;
    const int wid = tid >> 6;     // 0..7
    const int wc  = wid & 3;      // code group: codes wc*128..+128 within tile
    const int wr  = wid >> 2;     // row group: rows wr*64..+64
    const long row0 = (long)blockIdx.x * RB;

    // chunk swizzle s(row) = (row>>1)&3: bijective over 8-row groups (both-sides, rule #21)
    auto stage = [&](int buf, int ct, int t) {
        {   // X slice: 128 rows x 64 B
            int row = wid * 16 + (l >> 2);
            int c   = l & 3;
            const unsigned char* g = (const unsigned char*)X1
                + (row0 + row) * ROWB + t * 64 + ((c ^ ((row >> 1) & 3)) << 4);
            load16(g, lds + 65536 + buf * 8192 + wid * 1024);
        }
#pragma unroll
        for (int h = 0; h < 4; ++h) {   // E slice: 512 rows x 64 B
            int row = wid * 64 + h * 16 + (l >> 2);
            int c   = l & 3;
            const unsigned char* g = (const unsigned char*)E1
                + (long)(ct * CT + row) * ROWB + t * 64 + ((c ^ ((row >> 1) & 3)) << 4);
            load16(g, lds + buf * 32768 + wid * 4096 + h * 1024);
        }
    };

    // per-lane running top-2 per xn tile (each lane sees 64 codes/tile for its 2 rows)
    float q0[2], q1[2]; int i0[2], i1[2];
#pragma unroll
    for (int xn = 0; xn < 2; ++xn) { q0[xn] = -3.0e38f; q1[xn] = -3.0e38f; i0[xn] = 0; i1[xn] = 0; }

    f32x16 acc[4][2];
    int cur = 0;
    stage(0, 0, 0);
    __syncthreads();

    const int kg = l >> 5;        // K half-group for A/B frags
    const int lm = l & 31;        // M/N index within 32-tile

    for (int ct = 0; ct < NCT; ++ct) {
#pragma unroll
        for (int cm = 0; cm < 4; ++cm)
#pragma unroll
            for (int xn = 0; xn < 2; ++xn)
#pragma unroll
                for (int r = 0; r < 16; ++r) acc[cm][xn][r] = 0.0f;

        for (int t = 0; t < NKS; ++t) {
            if (t + 1 < NKS)          stage(cur ^ 1, ct, t + 1);
            else if (ct + 1 < NCT)    stage(cur ^ 1, ct + 1, 0);

            const unsigned char* Es = lds + cur * 32768;
            const unsigned char* Xs = lds + 65536 + cur * 8192;

            // frags: 2 K-substeps (K=16 each) per 32-K phase
            f16x8 afr[4][2], bfr[2][2];
#pragma unroll
            for (int ks = 0; ks < 2; ++ks) {
                const int gk = ks * 2 + kg;   // global 16B chunk within 64B row slice
#pragma unroll
                for (int cm = 0; cm < 4; ++cm) {
                    int row = wc * 128 + cm * 32 + lm;
                    afr[cm][ks] = *(const f16x8*)(Es + row * 64 + ((gk ^ ((row >> 1) & 3)) << 4));
                }
#pragma unroll
                for (int xn = 0; xn < 2; ++xn) {
                    int row = wr * 64 + xn * 32 + lm;
                    bfr[xn][ks] = *(const f16x8*)(Xs + row * 64 + ((gk ^ ((row >> 1) & 3)) << 4));
                }
            }

            __builtin_amdgcn_s_setprio(1);
#pragma unroll
            for (int ks = 0; ks < 2; ++ks)
#pragma unroll
                for (int cm = 0; cm < 4; ++cm)
#pragma unroll
                    for (int xn = 0; xn < 2; ++xn)
                        acc[cm][xn] = __builtin_amdgcn_mfma_f32_32x32x16_f16(
                            afr[cm][ks], bfr[xn][ks], acc[cm][xn], 0, 0, 0);
            __builtin_amdgcn_s_setprio(0);

            __syncthreads();
            cur ^= 1;
        }

        // insert this tile's values into per-lane top-2.
        // C/D layout (32x32): col(=x-row)=l&31, row(=code)=(r&3)+8*(r>>2)+4*kg
#pragma unroll
        for (int xn = 0; xn < 2; ++xn) {
#pragma unroll
            for (int cm = 0; cm < 4; ++cm) {
                const int cbase = ct * CT + wc * 128 + cm * 32 + 4 * kg;
#pragma unroll
                for (int r = 0; r < 16; ++r) {
                    float v = acc[cm][xn][r];
                    int  cc = cbase + (r & 3) + 8 * (r >> 2);
                    bool b0 = v > q0[xn];
                    bool b1 = v > q1[xn];
                    q1[xn] = b1 ? (b0 ? q0[xn] : v)  : q1[xn];
                    i1[xn] = b1 ? (b0 ? i0[xn] : cc) : i1[xn];
                    q0[xn] = b0 ? v  : q0[xn];
                    i0[xn] = b0 ? cc : i0[xn];
                }
            }
        }
    }

    // merge: 16 candidates/row via LDS -> exact top-4 -> cand[]
    __syncthreads();
    float2* cl = (float2*)lds;            // [128 rows][16 slots]
#pragma unroll
    for (int xn = 0; xn < 2; ++xn) {
        int rl = wr * 64 + xn * 32 + lm;
        cl[rl * 16 + wc * 4 + kg * 2 + 0] = make_float2(q0[xn], __int_as_float(i0[xn]));
        cl[rl * 16 + wc * 4 + kg * 2 + 1] = make_float2(q1[xn], __int_as_float(i1[xn]));
    }
    __syncthreads();

    if (tid < RB) {
        float t0 = -3.0e38f, t1 = -3.0e38f, t2 = -3.0e38f, t3 = -3.0e38f;
        int   u0 = 0, u1 = 0, u2 = 0, u3 = 0;
        for (int k = 0; k < 16; ++k) {
            float2 p = cl[tid * 16 + k];
            float v = p.x; int cc = __float_as_int(p.y);
            bool b0 = v > t0, b1 = v > t1, b2 = v > t2, b3 = v > t3;
            t3 = b3 ? (b2 ? t2 : v)  : t3;  u3 = b3 ? (b2 ? u2 : cc) : u3;
            t2 = b2 ? (b1 ? t1 : v)  : t2;  u2 = b2 ? (b1 ? u1 : cc) : u2;
            t1 = b1 ? (b0 ? t0 : v)  : t1;  u1 = b1 ? (b0 ? u0 : cc) : u1;
            t0 = b0 ? v : t0;               u0 = b0 ? cc : u0;
        }
        int4 w; w.x = u0; w.y = u1; w.z = u2; w.w = u3;
        *(int4*)(cand + (row0 + tid) * 4) = w;
    }
}

// exact fp32 rerank of the 4 candidates + gather e[winner] -> out
__global__ __launch_bounds__(256)
void rerank_gather(const float* __restrict__ x, const float* __restrict__ e,
                   const int* __restrict__ cand, float* __restrict__ out) {
    const int tid = threadIdx.x;
    const int l   = tid & 63;
    const int w   = tid >> 6;
    const long row = (long)blockIdx.x * 4 + w;

    const float* xr = x + row * K_DIM + l * 8;
    f32x4 xv0 = *(const f32x4*)(xr);
    f32x4 xv1 = *(const f32x4*)(xr + 4);

    float d[4]; int c[4];
#pragma unroll
    for (int i = 0; i < 4; ++i) {
        c[i] = cand[row * 4 + i];
        const float* er = e + (long)c[i] * K_DIM + l * 8;
        f32x4 ev0 = *(const f32x4*)(er);
        f32x4 ev1 = *(const f32x4*)(er + 4);
        float s = 0.0f;
        s = fmaf(xv0[0], ev0[0], s); s = fmaf(xv0[1], ev0[1], s);
        s = fmaf(xv0[2], ev0[2], s); s = fmaf(xv0[3], ev0[3], s);
        s = fmaf(xv1[0], ev1[0], s); s = fmaf(xv1[1], ev1[1], s);
        s = fmaf(xv1[2], ev1[2], s); s = fmaf(xv1[3], ev1[3], s);
        d[i] = s;
    }
#pragma unroll
    for (int m = 1; m < 64; m <<= 1)
#pragma unroll
        for (int i = 0; i < 4; ++i) d[i] += __shfl_xor(d[i], m);

    float bv = d[0]; int bc = c[0];
#pragma unroll
    for (int i = 1; i < 4; ++i)
        if (d[i] > bv || (d[i] == bv && c[i] < bc)) { bv = d[i]; bc = c[i]; }

    const float4* src = (const float4*)(e + (long)bc * K_DIM) + l * 2;
    float4*       dst = (float4*)(out + row * K_DIM) + l * 2;
    dst[0] = src[0];
    dst[1] = src[1];
}

extern "C" void kernel_launch(void* const* d_in, const int* in_sizes, int n_in,
                              void* d_out, int out_size, void* d_ws, size_t ws_size,
                              hipStream_t stream) {
    const float* x = (const float*)d_in[0];   // [M, 512] fp32
    const float* e = (const float*)d_in[1];   // [4096, 512] fp32
    float* out = (float*)d_out;

    const int M  = in_sizes[0] / K_DIM;       // 32768
    const int Ce = in_sizes[1] / K_DIM;       // 4096

    _Float16* X1 = (_Float16*)d_out;                                   // 32 MiB, dead before out written
    _Float16* E1 = (_Float16*)d_ws;                                    // 4 MiB
    int* cand    = (int*)((char*)d_ws + (size_t)Ce * K_DIM * 2);       // M*4 ints

    const int xb = M / 4, eb = Ce / 4;
    convert_f16<<<xb + eb, 256, 0, stream>>>(x, e, X1, E1, xb);
    vq_gemm<<<M / RB, 512, 81920, stream>>>(X1, E1, cand);
    rerank_gather<<<M / 4, 256, 0, stream>>>(x, e, cand, out);
}

// Round 7
// 223.753 us; speedup vs baseline: 1.3656x; 1.0467x over previous
//
#include <hip/hip_runtime.h>

#define K_DIM  512
#define C_DIM  4096
#define RB     128           // x-rows per workgroup
#define CT     512           // codes per tile
#define NCT    (C_DIM / CT)  // 8
#define NKS    8             // K-steps of 64 per ct sweep
#define ROWB   1024          // bytes per fp16 row (512 * 2)
// LDS: Es dbuf 2x64KB at [0]; Xs dbuf 2x16KB at [131072]; 160 KB total

typedef __attribute__((ext_vector_type(4)))  float    f32x4;
typedef __attribute__((ext_vector_type(16))) float    f32x16;
typedef _Float16 __attribute__((ext_vector_type(8)))  f16x8;

__device__ __forceinline__ void load16(const void* g, void* s) {
    __builtin_amdgcn_global_load_lds(
        (const __attribute__((address_space(1))) unsigned int*)g,
        (__attribute__((address_space(3))) unsigned int*)s, 16, 0, 0);
}

// prepass: x -> X1 fp16 (in d_out), e -> E1 fp16 (in ws)
__global__ __launch_bounds__(256)
void convert_f16(const float* __restrict__ x, const float* __restrict__ e,
                 _Float16* __restrict__ X1, _Float16* __restrict__ E1, int xblocks) {
    const long bid = blockIdx.x;
    const float* src; _Float16* dst; long base;
    if (bid < xblocks) { src = x; dst = X1; base = (bid * 256 + threadIdx.x) * 8L; }
    else               { src = e; dst = E1; base = ((bid - xblocks) * 256 + threadIdx.x) * 8L; }
    float4 v0 = *(const float4*)(src + base);
    float4 v1 = *(const float4*)(src + base + 4);
    f16x8 h;
    h[0] = (_Float16)v0.x; h[1] = (_Float16)v0.y; h[2] = (_Float16)v0.z; h[3] = (_Float16)v0.w;
    h[4] = (_Float16)v1.x; h[5] = (_Float16)v1.y; h[6] = (_Float16)v1.z; h[7] = (_Float16)v1.w;
    *(f16x8*)(dst + base) = h;
}

// fp16 proxy GEMM (swapped operands: MFMA A = codes, B = x-rows) + top-4 candidates.
// R6 barrier structure; K=64 per phase (64 phases total); full 8-chunk XOR swizzle.
__global__ __launch_bounds__(512, 2)
void vq_gemm(const _Float16* __restrict__ X1,
             const _Float16* __restrict__ E1,
             int* __restrict__ cand) {
    extern __shared__ unsigned char lds[];

    const int tid = threadIdx.x;
    const int l   = tid & 63;
    const int wid = tid >> 6;     // 0..7
    const int wc  = wid & 3;      // code group: codes wc*128..+128 within tile
    const int wr  = wid >> 2;     // row group: rows wr*64..+64
    const long row0 = (long)blockIdx.x * RB;

    // rows are 128 B in LDS; granule = (chunk ^ (row&7)) -> perfect 8-row bijection.
    // Pre-swizzled global source + same XOR on reads (both-sides, rule #21).
    auto stage = [&](int buf, int ct, int t) {
#pragma unroll
        for (int i = 0; i < 2; ++i) {   // X slice: 128 rows x 128 B
            int row = wid * 16 + i * 8 + (l >> 3);
            int c   = l & 7;
            const unsigned char* g = (const unsigned char*)X1
                + (row0 + row) * ROWB + t * 128 + ((c ^ (row & 7)) << 4);
            load16(g, lds + 131072 + buf * 16384 + wid * 2048 + i * 1024);
        }
#pragma unroll
        for (int h = 0; h < 8; ++h) {   // E slice: 512 rows x 128 B
            int row = wid * 64 + h * 8 + (l >> 3);
            int c   = l & 7;
            const unsigned char* g = (const unsigned char*)E1
                + (long)(ct * CT + row) * ROWB + t * 128 + ((c ^ (row & 7)) << 4);
            load16(g, lds + buf * 65536 + wid * 8192 + h * 1024);
        }
    };

    // per-lane running top-2 per xn tile
    float q0[2], q1[2]; int i0[2], i1[2];
#pragma unroll
    for (int xn = 0; xn < 2; ++xn) { q0[xn] = -3.0e38f; q1[xn] = -3.0e38f; i0[xn] = 0; i1[xn] = 0; }

    f32x16 acc[4][2];
    int cur = 0;
    stage(0, 0, 0);
    __syncthreads();

    const int kg = l >> 5;        // K half-group for A/B frags
    const int lm = l & 31;        // M/N index within 32-tile

    for (int ct = 0; ct < NCT; ++ct) {
#pragma unroll
        for (int cm = 0; cm < 4; ++cm)
#pragma unroll
            for (int xn = 0; xn < 2; ++xn)
#pragma unroll
                for (int r = 0; r < 16; ++r) acc[cm][xn][r] = 0.0f;

        for (int t = 0; t < NKS; ++t) {
            if (t + 1 < NKS)          stage(cur ^ 1, ct, t + 1);
            else if (ct + 1 < NCT)    stage(cur ^ 1, ct + 1, 0);

            const unsigned char* Es = lds + cur * 65536;
            const unsigned char* Xs = lds + 131072 + cur * 16384;

            // 4 K16 sub-steps; frag chunk index = ks*2 + kg within the 128 B row slice
#pragma unroll
            for (int ks = 0; ks < 4; ++ks) {
                const int gk = ks * 2 + kg;
                f16x8 afr[4], bfr[2];
#pragma unroll
                for (int cm = 0; cm < 4; ++cm) {
                    int row = wc * 128 + cm * 32 + lm;
                    afr[cm] = *(const f16x8*)(Es + row * 128 + ((gk ^ (row & 7)) << 4));
                }
#pragma unroll
                for (int xn = 0; xn < 2; ++xn) {
                    int row = wr * 64 + xn * 32 + lm;
                    bfr[xn] = *(const f16x8*)(Xs + row * 128 + ((gk ^ (row & 7)) << 4));
                }
                __builtin_amdgcn_s_setprio(1);
#pragma unroll
                for (int cm = 0; cm < 4; ++cm)
#pragma unroll
                    for (int xn = 0; xn < 2; ++xn)
                        acc[cm][xn] = __builtin_amdgcn_mfma_f32_32x32x16_f16(
                            afr[cm], bfr[xn], acc[cm][xn], 0, 0, 0);
                __builtin_amdgcn_s_setprio(0);
            }

            __syncthreads();
            cur ^= 1;
        }

        // insert this tile's values into per-lane top-2.
        // C/D layout (32x32): col(=x-row)=l&31, row(=code)=(r&3)+8*(r>>2)+4*kg
#pragma unroll
        for (int xn = 0; xn < 2; ++xn) {
#pragma unroll
            for (int cm = 0; cm < 4; ++cm) {
                const int cbase = ct * CT + wc * 128 + cm * 32 + 4 * kg;
#pragma unroll
                for (int r = 0; r < 16; ++r) {
                    float v = acc[cm][xn][r];
                    int  cc = cbase + (r & 3) + 8 * (r >> 2);
                    bool b0 = v > q0[xn];
                    bool b1 = v > q1[xn];
                    q1[xn] = b1 ? (b0 ? q0[xn] : v)  : q1[xn];
                    i1[xn] = b1 ? (b0 ? i0[xn] : cc) : i1[xn];
                    q0[xn] = b0 ? v  : q0[xn];
                    i0[xn] = b0 ? cc : i0[xn];
                }
            }
        }
    }

    // merge: 16 candidates/row via LDS -> exact top-4 -> cand[]
    __syncthreads();
    float2* cl = (float2*)lds;            // [128 rows][16 slots]
#pragma unroll
    for (int xn = 0; xn < 2; ++xn) {
        int rl = wr * 64 + xn * 32 + lm;
        cl[rl * 16 + wc * 4 + kg * 2 + 0] = make_float2(q0[xn], __int_as_float(i0[xn]));
        cl[rl * 16 + wc * 4 + kg * 2 + 1] = make_float2(q1[xn], __int_as_float(i1[xn]));
    }
    __syncthreads();

    if (tid < RB) {
        float t0 = -3.0e38f, t1 = -3.0e38f, t2 = -3.0e38f, t3 = -3.0e38f;
        int   u0 = 0, u1 = 0, u2 = 0, u3 = 0;
        for (int k = 0; k < 16; ++k) {
            float2 p = cl[tid * 16 + k];
            float v = p.x; int cc = __float_as_int(p.y);
            bool b0 = v > t0, b1 = v > t1, b2 = v > t2, b3 = v > t3;
            t3 = b3 ? (b2 ? t2 : v)  : t3;  u3 = b3 ? (b2 ? u2 : cc) : u3;
            t2 = b2 ? (b1 ? t1 : v)  : t2;  u2 = b2 ? (b1 ? u1 : cc) : u2;
            t1 = b1 ? (b0 ? t0 : v)  : t1;  u1 = b1 ? (b0 ? u0 : cc) : u1;
            t0 = b0 ? v : t0;               u0 = b0 ? cc : u0;
        }
        int4 w; w.x = u0; w.y = u1; w.z = u2; w.w = u3;
        *(int4*)(cand + (row0 + tid) * 4) = w;
    }
}

// exact fp32 rerank of the 4 candidates + gather e[winner] -> out
__global__ __launch_bounds__(256)
void rerank_gather(const float* __restrict__ x, const float* __restrict__ e,
                   const int* __restrict__ cand, float* __restrict__ out) {
    const int tid = threadIdx.x;
    const int l   = tid & 63;
    const int w   = tid >> 6;
    const long row = (long)blockIdx.x * 4 + w;

    const float* xr = x + row * K_DIM + l * 8;
    f32x4 xv0 = *(const f32x4*)(xr);
    f32x4 xv1 = *(const f32x4*)(xr + 4);

    float d[4]; int c[4];
#pragma unroll
    for (int i = 0; i < 4; ++i) {
        c[i] = cand[row * 4 + i];
        const float* er = e + (long)c[i] * K_DIM + l * 8;
        f32x4 ev0 = *(const f32x4*)(er);
        f32x4 ev1 = *(const f32x4*)(er + 4);
        float s = 0.0f;
        s = fmaf(xv0[0], ev0[0], s); s = fmaf(xv0[1], ev0[1], s);
        s = fmaf(xv0[2], ev0[2], s); s = fmaf(xv0[3], ev0[3], s);
        s = fmaf(xv1[0], ev1[0], s); s = fmaf(xv1[1], ev1[1], s);
        s = fmaf(xv1[2], ev1[2], s); s = fmaf(xv1[3], ev1[3], s);
        d[i] = s;
    }
#pragma unroll
    for (int m = 1; m < 64; m <<= 1)
#pragma unroll
        for (int i = 0; i < 4; ++i) d[i] += __shfl_xor(d[i], m);

    float bv = d[0]; int bc = c[0];
#pragma unroll
    for (int i = 1; i < 4; ++i)
        if (d[i] > bv || (d[i] == bv && c[i] < bc)) { bv = d[i]; bc = c[i]; }

    const float4* src = (const float4*)(e + (long)bc * K_DIM) + l * 2;
    float4*       dst = (float4*)(out + row * K_DIM) + l * 2;
    dst[0] = src[0];
    dst[1] = src[1];
}

extern "C" void kernel_launch(void* const* d_in, const int* in_sizes, int n_in,
                              void* d_out, int out_size, void* d_ws, size_t ws_size,
                              hipStream_t stream) {
    const float* x = (const float*)d_in[0];   // [M, 512] fp32
    const float* e = (const float*)d_in[1];   // [4096, 512] fp32
    float* out = (float*)d_out;

    const int M  = in_sizes[0] / K_DIM;       // 32768
    const int Ce = in_sizes[1] / K_DIM;       // 4096

    _Float16* X1 = (_Float16*)d_out;                                   // 32 MiB, dead before out written
    _Float16* E1 = (_Float16*)d_ws;                                    // 4 MiB
    int* cand    = (int*)((char*)d_ws + (size_t)Ce * K_DIM * 2);       // M*4 ints

    // allow 160 KB dynamic LDS (defensive; ignore error if already allowed)
    (void)hipFuncSetAttribute((const void*)vq_gemm,
                              hipFuncAttributeMaxDynamicSharedMemorySize, 163840);

    const int xb = M / 4, eb = Ce / 4;
    convert_f16<<<xb + eb, 256, 0, stream>>>(x, e, X1, E1, xb);
    vq_gemm<<<M / RB, 512, 163840, stream>>>(X1, E1, cand);
    rerank_gather<<<M / 4, 256, 0, stream>>>(x, e, cand, out);
}